// Round 9
// baseline (449.181 us; speedup 1.0000x reference)
//
#include <hip/hip_runtime.h>

#define D 128

typedef short s16x8 __attribute__((ext_vector_type(8)));
typedef float f32x4 __attribute__((ext_vector_type(4)));

// ---------- helpers ----------

__device__ __forceinline__ unsigned int encf(float f) {
  unsigned int u = __float_as_uint(f);
  return (u & 0x80000000u) ? ~u : (u | 0x80000000u);
}
__device__ __forceinline__ unsigned short f2bf(float f) {
  unsigned int u = __float_as_uint(f);
  u += 0x7FFFu + ((u >> 16) & 1u);  // rne
  return (unsigned short)(u >> 16);
}
__device__ __forceinline__ float bf_lo(unsigned int u) {
  return __uint_as_float(u << 16);
}
__device__ __forceinline__ float bf_hi(unsigned int u) {
  return __uint_as_float(u & 0xFFFF0000u);
}

// JAX threefry2x32 (20 rounds), exact.
__device__ __forceinline__ void tf2x32(unsigned int k0, unsigned int k1,
                                       unsigned int& x0, unsigned int& x1) {
  unsigned int ks[3] = {k0, k1, k0 ^ k1 ^ 0x1BD11BDAu};
  x0 += ks[0]; x1 += ks[1];
  const unsigned int rotA[4] = {13u, 15u, 26u, 6u};
  const unsigned int rotB[4] = {17u, 29u, 16u, 24u};
#pragma unroll
  for (int g = 0; g < 5; ++g) {
    const unsigned int* rot = (g & 1) ? rotB : rotA;
#pragma unroll
    for (int i = 0; i < 4; ++i) {
      x0 += x1;
      x1 = (x1 << rot[i]) | (x1 >> (32u - rot[i]));
      x1 ^= x0;
    }
    x0 += ks[(g + 1) % 3];
    x1 += ks[(g + 2) % 3] + (unsigned int)(g + 1);
  }
}

// per-block int64-vs-int32 edge layout detect (wave-0 ballot over odd words)
__device__ __forceinline__ int detect64(const int* ei) {
  int v = 0;
  int tid = threadIdx.x;
  if (tid < 64) v = ei[2 * tid + 1];
  unsigned long long b = __ballot(v != 0);
  return b == 0ull;  // all-high-words-zero -> int64
}

// ---------- MFMA bf16 GEMM: Y = bf16(X @ W^T), exact grid (1 tile/block) ----

__device__ __forceinline__ int swz(int row, int kb) {
  return row * 256 + (kb ^ ((row & 7) << 4));
}

__global__ __launch_bounds__(256) void gemm_bf16(const float* __restrict__ X,
                                                 const float* __restrict__ W,
                                                 unsigned short* __restrict__ Y,
                                                 int N) {
  __shared__ __align__(16) unsigned short As[128 * 128];
  __shared__ __align__(16) unsigned short Bs[128 * 128];
  const int tid = threadIdx.x;
  const long long r0 = (long long)blockIdx.x * 128;

#pragma unroll 4
  for (int i = 0; i < 16; ++i) {
    int f = i * 256 + tid;
    int row = f >> 5;
    int j = f & 31;
    float4 wv = *(const float4*)(W + row * D + j * 4);
    uint2 wp;
    wp.x = (unsigned int)f2bf(wv.x) | ((unsigned int)f2bf(wv.y) << 16);
    wp.y = (unsigned int)f2bf(wv.z) | ((unsigned int)f2bf(wv.w) << 16);
    *(uint2*)((char*)Bs + swz(row, j * 8)) = wp;
    long long rr = r0 + row;
    if (rr >= N) rr = N - 1;
    float4 xv = *(const float4*)(X + rr * D + j * 4);
    uint2 xp;
    xp.x = (unsigned int)f2bf(xv.x) | ((unsigned int)f2bf(xv.y) << 16);
    xp.y = (unsigned int)f2bf(xv.z) | ((unsigned int)f2bf(xv.w) << 16);
    *(uint2*)((char*)As + swz(row, j * 8)) = xp;
  }
  __syncthreads();

  const int lane = tid & 63;
  const int wid = tid >> 6;
  const int wr = wid >> 1;
  const int wc = wid & 1;
  const int cl = lane & 15;
  const int sub = lane >> 4;

  f32x4 acc[4][4] = {};

#pragma unroll
  for (int ks = 0; ks < 4; ++ks) {
    s16x8 av[4], bv[4];
#pragma unroll
    for (int m = 0; m < 4; ++m)
      av[m] = *(const s16x8*)((const char*)As +
                              swz(wr * 64 + m * 16 + cl, ks * 64 + sub * 16));
#pragma unroll
    for (int n = 0; n < 4; ++n)
      bv[n] = *(const s16x8*)((const char*)Bs +
                              swz(wc * 64 + n * 16 + cl, ks * 64 + sub * 16));
#pragma unroll
    for (int m = 0; m < 4; ++m)
#pragma unroll
      for (int n = 0; n < 4; ++n)
        acc[m][n] = __builtin_amdgcn_mfma_f32_16x16x32_bf16(av[m], bv[n],
                                                            acc[m][n], 0, 0, 0);
  }

#pragma unroll
  for (int m = 0; m < 4; ++m) {
#pragma unroll
    for (int j = 0; j < 4; ++j) {
      long long row = r0 + wr * 64 + m * 16 + sub * 4 + j;
      if (row < N) {
        unsigned short* yp = Y + row * D + wc * 64 + cl;
#pragma unroll
        for (int n = 0; n < 4; ++n) yp[n * 16] = f2bf(acc[m][n][j]);
      }
    }
  }
}

// ---------- edge pass 1: score -> store exp(e), atomicAdd denom ----------
// Inline edge decode; 2048 wg (TLP-bound gather: 72% occ = 50us, 37% = 55us).

__global__ __launch_bounds__(256) void edge_scores(
    const unsigned short* __restrict__ xlh, const unsigned short* __restrict__ xrh,
    const int* __restrict__ ei, const float* __restrict__ att,
    float* __restrict__ e_ex, float* __restrict__ s_sum, int ne, int ns,
    int nm) {
  __shared__ int f64s;
  int tid = threadIdx.x;
  int d64 = detect64(ei);
  if (tid == 0) f64s = d64;
  __syncthreads();
  const int f64 = f64s;

  int lane = tid & 63;
  int q = lane & 15;
  int sub = lane >> 4;
  int wid = (blockIdx.x * 256 + tid) >> 6;
  int nw = (gridDim.x * 256) >> 6;
  float4 a0 = ((const float4*)att)[2 * q];
  float4 a1 = ((const float4*)att)[2 * q + 1];
  for (int e0 = wid * 8; e0 < ne; e0 += nw * 8) {
    int eA = e0 + sub, eB = e0 + 4 + sub;
    int okA = eA < ne, okB = eB < ne;
    int sA = 0, dA = 0, sB = 0, dB = 0;
    if (okA) {
      sA = f64 ? ei[2 * eA] : ei[eA];
      dA = f64 ? ei[2 * ne + 2 * eA] : ei[ne + eA];
      sA = sA < 0 ? 0 : (sA >= ns ? ns - 1 : sA);
      dA = dA < 0 ? 0 : (dA >= nm ? nm - 1 : dA);
    }
    if (okB) {
      sB = f64 ? ei[2 * eB] : ei[eB];
      dB = f64 ? ei[2 * ne + 2 * eB] : ei[ne + eB];
      sB = sB < 0 ? 0 : (sB >= ns ? ns - 1 : sB);
      dB = dB < 0 ? 0 : (dB >= nm ? nm - 1 : dB);
    }
    uint4 lA = *(const uint4*)(xlh + (long long)sA * D + q * 8);
    uint4 rA = *(const uint4*)(xrh + (long long)dA * D + q * 8);
    uint4 lB = *(const uint4*)(xlh + (long long)sB * D + q * 8);
    uint4 rB = *(const uint4*)(xrh + (long long)dB * D + q * 8);
    float z, vA = 0.f, vB = 0.f;
    z = bf_lo(lA.x) + bf_lo(rA.x); vA += (z > 0.f ? z : 0.2f * z) * a0.x;
    z = bf_hi(lA.x) + bf_hi(rA.x); vA += (z > 0.f ? z : 0.2f * z) * a0.y;
    z = bf_lo(lA.y) + bf_lo(rA.y); vA += (z > 0.f ? z : 0.2f * z) * a0.z;
    z = bf_hi(lA.y) + bf_hi(rA.y); vA += (z > 0.f ? z : 0.2f * z) * a0.w;
    z = bf_lo(lA.z) + bf_lo(rA.z); vA += (z > 0.f ? z : 0.2f * z) * a1.x;
    z = bf_hi(lA.z) + bf_hi(rA.z); vA += (z > 0.f ? z : 0.2f * z) * a1.y;
    z = bf_lo(lA.w) + bf_lo(rA.w); vA += (z > 0.f ? z : 0.2f * z) * a1.z;
    z = bf_hi(lA.w) + bf_hi(rA.w); vA += (z > 0.f ? z : 0.2f * z) * a1.w;
    z = bf_lo(lB.x) + bf_lo(rB.x); vB += (z > 0.f ? z : 0.2f * z) * a0.x;
    z = bf_hi(lB.x) + bf_hi(rB.x); vB += (z > 0.f ? z : 0.2f * z) * a0.y;
    z = bf_lo(lB.y) + bf_lo(rB.y); vB += (z > 0.f ? z : 0.2f * z) * a0.z;
    z = bf_hi(lB.y) + bf_hi(rB.y); vB += (z > 0.f ? z : 0.2f * z) * a0.w;
    z = bf_lo(lB.z) + bf_lo(rB.z); vB += (z > 0.f ? z : 0.2f * z) * a1.x;
    z = bf_hi(lB.z) + bf_hi(rB.z); vB += (z > 0.f ? z : 0.2f * z) * a1.y;
    z = bf_lo(lB.w) + bf_lo(rB.w); vB += (z > 0.f ? z : 0.2f * z) * a1.z;
    z = bf_hi(lB.w) + bf_hi(rB.w); vB += (z > 0.f ? z : 0.2f * z) * a1.w;
#pragma unroll
    for (int o = 8; o > 0; o >>= 1) vA += __shfl_xor(vA, o, 64);
#pragma unroll
    for (int o = 8; o > 0; o >>= 1) vB += __shfl_xor(vB, o, 64);
    if (q == 0) {
      if (okA) { float ex = expf(vA); e_ex[eA] = ex; atomicAdd(&s_sum[dA], ex); }
      if (okB) { float ex = expf(vB); e_ex[eB] = ex; atomicAdd(&s_sum[dB], ex); }
    }
  }
}

// ---------- edge pass 2: per-source scalar coefficients (grid-stride) ------

__global__ __launch_bounds__(256) void edge_coef(
    const float* __restrict__ e_ex, const int* __restrict__ ei,
    const float* __restrict__ s_sum, float* __restrict__ coef, int ne, int ns,
    int nm) {
  __shared__ int f64s;
  int tid = threadIdx.x;
  int d64 = detect64(ei);
  if (tid == 0) f64s = d64;
  __syncthreads();
  const int f64 = f64s;
  for (int i = blockIdx.x * 256 + tid; i < ne; i += gridDim.x * 256) {
    int s_ = f64 ? ei[2 * i] : ei[i];
    int d_ = f64 ? ei[2 * ne + 2 * i] : ei[ne + i];
    s_ = s_ < 0 ? 0 : (s_ >= ns ? ns - 1 : s_);
    d_ = d_ < 0 ? 0 : (d_ >= nm ? nm - 1 : d_);
    float w = e_ex[i] / s_sum[d_];
    atomicAdd(&coef[s_], w);
  }
}

// ---------- edge pass 3: g_vec[d] = sum_s coef[s] * xlh[s][d]  (bf16 rows) ----

__global__ __launch_bounds__(256) void weighted_sum(
    const unsigned short* __restrict__ xlh, const float* __restrict__ coef,
    float* __restrict__ g_vec, int ns) {
  __shared__ float red[4][D];
  int lane = threadIdx.x & 63;
  int wv = threadIdx.x >> 6;
  int wid = blockIdx.x * 4 + wv;
  int nw = gridDim.x * 4;
  float ax = 0.f, ay = 0.f;
  for (int s = wid; s < ns; s += nw) {
    float w = coef[s];
    unsigned int x2 = ((const unsigned int*)(xlh + (long long)s * D))[lane];
    ax += w * bf_lo(x2);
    ay += w * bf_hi(x2);
  }
  red[wv][2 * lane] = ax;
  red[wv][2 * lane + 1] = ay;
  __syncthreads();
  if (threadIdx.x < D) {
    float t = red[0][threadIdx.x] + red[1][threadIdx.x] + red[2][threadIdx.x] +
              red[3][threadIdx.x];
    atomicAdd(&g_vec[threadIdx.x], t);
  }
}

// ---------- per step, part 1: gates, 32 blocks, coalesced ----------

__global__ __launch_bounds__(256) void lstm_gates(
    const float* __restrict__ g_vec, const float* __restrict__ conv_bias,
    const float* __restrict__ Wih, const float* __restrict__ Whh,
    const float* __restrict__ bih, const float* __restrict__ bhh,
    const float* __restrict__ emb, const float* __restrict__ logits,
    const unsigned long long* __restrict__ amax,
    const float* __restrict__ sumexp, const float* __restrict__ st_h,
    float* __restrict__ st_gates, float* __restrict__ out, int nm, float nmf,
    int t) {
  __shared__ float vin[D], hprev[D];
  const int tid = threadIdx.x;

  int a = 0;
  if (t > 0) {
    unsigned long long p = amax[t - 1];
    a = (int)(0xFFFFFFFFu - (unsigned int)(p & 0xFFFFFFFFull));
    a = a < 0 ? 0 : (a >= nm ? nm - 1 : a);
  }
  if (t > 0 && blockIdx.x == 0 && tid == 0) {
    out[t - 1] = (float)a;
    out[8 + t - 1] = logits[a] - logf(sumexp[t - 1]);
  }
  if (tid < D) {
    vin[tid] = (t == 0) ? (g_vec[tid] / nmf + conv_bias[tid])
                        : emb[(long long)a * D + tid];
    hprev[tid] = (t == 0) ? 0.f : st_h[tid];
  }
  __syncthreads();

  int r = blockIdx.x * 16 + (tid >> 4);
  int q = tid & 15;
  const float4* wi = (const float4*)(Wih + (long long)r * D + q * 8);
  const float4* wh = (const float4*)(Whh + (long long)r * D + q * 8);
  float4 a0 = wi[0], a1 = wi[1];
  float4 b0 = wh[0], b1 = wh[1];
  int kb = q * 8;
  float s = a0.x * vin[kb] + a0.y * vin[kb + 1] + a0.z * vin[kb + 2] +
            a0.w * vin[kb + 3] + a1.x * vin[kb + 4] + a1.y * vin[kb + 5] +
            a1.z * vin[kb + 6] + a1.w * vin[kb + 7] + b0.x * hprev[kb] +
            b0.y * hprev[kb + 1] + b0.z * hprev[kb + 2] + b0.w * hprev[kb + 3] +
            b1.x * hprev[kb + 4] + b1.y * hprev[kb + 5] + b1.z * hprev[kb + 6] +
            b1.w * hprev[kb + 7];
  s += __shfl_xor(s, 1, 64);
  s += __shfl_xor(s, 2, 64);
  s += __shfl_xor(s, 4, 64);
  s += __shfl_xor(s, 8, 64);
  if (q == 0) st_gates[r] = s + bih[r] + bhh[r];
}

// ---------- per step, part 2: 512 wg grid-stride over W2 rows ----------
// Per block: cell+W1 prologue (redundant), then 64-row chunks; (pk,ex) in
// registers; ONE atomicMax+atomicAdd per block.

__global__ __launch_bounds__(256) void logits_fused3(
    const float* __restrict__ st_gates, const float* __restrict__ W1,
    const float* __restrict__ b1, const float* __restrict__ W2,
    const float* __restrict__ b2, float* __restrict__ st_c,
    float* __restrict__ st_h, float* __restrict__ logits,
    unsigned long long* __restrict__ amax, float* __restrict__ sumexp,
    int nm, int t) {
  __shared__ float hn_s[D];
  __shared__ float hid_s[D];
  __shared__ unsigned long long pkw[4];
  __shared__ float exw[4];
  const int tid = threadIdx.x;
  const int bid = blockIdx.x;

  if (tid < D) {
    float gi = st_gates[tid], gf = st_gates[D + tid],
          gg = st_gates[2 * D + tid], go = st_gates[3 * D + tid];
    float i_ = 1.f / (1.f + expf(-gi));
    float f_ = 1.f / (1.f + expf(-gf));
    float g_ = tanhf(gg);
    float o_ = 1.f / (1.f + expf(-go));
    float cprev = (t == 0) ? 0.f : st_c[((t & 1) ^ 1) * D + tid];
    float cn = f_ * cprev + i_ * g_;
    float hn = o_ * tanhf(cn);
    hn_s[tid] = hn;
    if (bid == 0) {
      st_c[(t & 1) * D + tid] = cn;
      st_h[tid] = hn;
    }
  }
  __syncthreads();

  if (tid < D) {
    const float4* w = (const float4*)(W1 + tid * D);
    float s0 = 0.f, s1 = 0.f, s2 = 0.f, s3 = 0.f;
#pragma unroll 8
    for (int k = 0; k < 32; ++k) {
      float4 ww = w[k];
      s0 += ww.x * hn_s[4 * k];
      s1 += ww.y * hn_s[4 * k + 1];
      s2 += ww.z * hn_s[4 * k + 2];
      s3 += ww.w * hn_s[4 * k + 3];
    }
    hid_s[tid] = fmaxf(((s0 + s1) + (s2 + s3)) + b1[tid], 0.f);
  }
  __syncthreads();

  // gumbel key for this step
  unsigned int k0 = 0u, k1 = (unsigned int)t;
  tf2x32(0u, 42u, k0, k1);

  const int q = tid & 3;
  float exacc = 0.f;
  unsigned long long pkacc = 0ull;
  for (int r0 = bid * 64; r0 < nm; r0 += gridDim.x * 64) {
    int row = r0 + (tid >> 2);
    if (row < nm) {
      const float4* w = (const float4*)(W2 + (long long)row * D + q * 32);
      float s0 = 0.f, s1 = 0.f, s2 = 0.f, s3 = 0.f;
#pragma unroll
      for (int k = 0; k < 8; ++k) {
        float4 ww = w[k];
        int kb = q * 32 + 4 * k;
        s0 += ww.x * hid_s[kb];
        s1 += ww.y * hid_s[kb + 1];
        s2 += ww.z * hid_s[kb + 2];
        s3 += ww.w * hid_s[kb + 3];
      }
      float s = (s0 + s1) + (s2 + s3);
      s += __shfl_xor(s, 1, 64);
      s += __shfl_xor(s, 2, 64);
      if (q == 0) {
        float lv = s + b2[row];
        logits[row] = lv;
        exacc += expf(lv);
        unsigned int x0 = 0u, x1 = (unsigned int)row;
        tf2x32(k0, k1, x0, x1);
        unsigned int bits = x0 ^ x1;
        float f = __uint_as_float((bits >> 9) | 0x3f800000u) - 1.0f;
        const float tiny = 1.1754943508222875e-38f;
        float u = fmaxf(tiny, f * (1.0f - tiny) + tiny);
        float gmb = -logf(-logf(u));
        float pert = lv + gmb;
        unsigned long long pk = ((unsigned long long)encf(pert) << 32) |
                                (unsigned long long)(0xFFFFFFFFu - (unsigned int)row);
        pkacc = pk > pkacc ? pk : pkacc;
      }
    }
  }
  // wave-level reduce (max pk, sum ex)
#pragma unroll
  for (int o = 32; o > 0; o >>= 1) {
    unsigned long long pko = __shfl_xor(pkacc, o, 64);
    pkacc = pko > pkacc ? pko : pkacc;
    exacc += __shfl_xor(exacc, o, 64);
  }
  int wv = tid >> 6;
  if ((tid & 63) == 0) {
    pkw[wv] = pkacc;
    exw[wv] = exacc;
  }
  __syncthreads();
  if (tid == 0) {
    unsigned long long pm = pkw[0];
    pm = pkw[1] > pm ? pkw[1] : pm;
    pm = pkw[2] > pm ? pkw[2] : pm;
    pm = pkw[3] > pm ? pkw[3] : pm;
    atomicMax(&amax[t], pm);
    atomicAdd(&sumexp[t], ((exw[0] + exw[1]) + (exw[2] + exw[3])));
  }
}

// ---------- final outputs ----------

__global__ __launch_bounds__(128) void final_out(
    const float* __restrict__ h, const float* __restrict__ c,
    const float* __restrict__ logits, const unsigned long long* __restrict__ amax,
    const float* __restrict__ sumexp, float* __restrict__ out, int nm) {
  int tid = threadIdx.x;
  if (tid == 0) {
    unsigned long long p = amax[7];
    int a = (int)(0xFFFFFFFFu - (unsigned int)(p & 0xFFFFFFFFull));
    a = a < 0 ? 0 : (a >= nm ? nm - 1 : a);
    out[7] = (float)a;
    out[15] = logits[a] - logf(sumexp[7]);
  }
  out[16 + tid] = h[tid];
  out[144 + tid] = c[tid];
}

// ---------- launch ----------

extern "C" void kernel_launch(void* const* d_in, const int* in_sizes, int n_in,
                              void* d_out, int out_size, void* d_ws, size_t ws_size,
                              hipStream_t stream) {
  const float* state_features = (const float*)d_in[0];
  const float* model_features = (const float*)d_in[1];
  const int* edge_index = (const int*)d_in[2];
  const float* W_l = (const float*)d_in[3];
  const float* W_r = (const float*)d_in[4];
  const float* att = (const float*)d_in[5];
  const float* conv_bias = (const float*)d_in[6];
  const float* Wih = (const float*)d_in[7];
  const float* Whh = (const float*)d_in[8];
  const float* bih = (const float*)d_in[9];
  const float* bhh = (const float*)d_in[10];
  const float* W1 = (const float*)d_in[11];
  const float* b1 = (const float*)d_in[12];
  const float* W2 = (const float*)d_in[13];
  const float* b2 = (const float*)d_in[14];
  const float* emb = (const float*)d_in[15];
  float* out = (float*)d_out;

  const int NS = in_sizes[0] / D;
  const int NM = in_sizes[1] / D;
  const int E = in_sizes[2] / 2;

  char* ws = (char*)d_ws;
  size_t off = 0;
  auto alloc = [&](size_t bytes) -> void* {
    void* p = ws + off;
    off = (off + bytes + 255) & ~(size_t)255;
    return p;
  };
  unsigned short* xlh = (unsigned short*)alloc((size_t)NS * D * 2);
  unsigned short* xrh = (unsigned short*)alloc((size_t)NM * D * 2);
  float* e_ex = (float*)alloc((size_t)E * 4);
  float* logits = (float*)alloc((size_t)NM * 4);
  float* st_h = (float*)alloc(D * 4);
  float* st_c = (float*)alloc(2 * D * 4);
  float* st_gates = (float*)alloc(4 * D * 4);
  size_t zstart = off;
  float* s_sum = (float*)alloc((size_t)NM * 4);
  float* coef = (float*)alloc((size_t)NS * 4);
  float* g_vec = (float*)alloc(D * 4);
  float* st_sumexp = (float*)alloc(8 * 4);
  unsigned long long* st_amax = (unsigned long long*)alloc(8 * 8);
  size_t zend = off;

  hipMemsetAsync(ws + zstart, 0, zend - zstart, stream);

  gemm_bf16<<<(NS + 127) / 128, 256, 0, stream>>>(state_features, W_l, xlh, NS);
  gemm_bf16<<<(NM + 127) / 128, 256, 0, stream>>>(model_features, W_r, xrh, NM);

  edge_scores<<<2048, 256, 0, stream>>>(xlh, xrh, edge_index, att, e_ex,
                                        s_sum, E, NS, NM);
  edge_coef<<<1024, 256, 0, stream>>>(e_ex, edge_index, s_sum, coef, E, NS,
                                      NM);
  weighted_sum<<<1024, 256, 0, stream>>>(xlh, coef, g_vec, NS);

  for (int t = 0; t < 8; ++t) {
    lstm_gates<<<32, 256, 0, stream>>>(g_vec, conv_bias, Wih, Whh, bih, bhh,
                                       emb, logits, st_amax, st_sumexp, st_h,
                                       st_gates, out, NM, (float)NM, t);
    logits_fused3<<<512, 256, 0, stream>>>(st_gates, W1, b1, W2, b2, st_c,
                                           st_h, logits, st_amax, st_sumexp,
                                           NM, t);
  }

  final_out<<<1, 128, 0, stream>>>(st_h, st_c + D, logits, st_amax, st_sumexp,
                                   out, NM);
}

// Round 10
// 413.264 us; speedup vs baseline: 1.0869x; 1.0869x over previous
//
#include <hip/hip_runtime.h>

#define D 128

typedef short s16x8 __attribute__((ext_vector_type(8)));
typedef float f32x4 __attribute__((ext_vector_type(4)));

// ---------- helpers ----------

__device__ __forceinline__ unsigned int encf(float f) {
  unsigned int u = __float_as_uint(f);
  return (u & 0x80000000u) ? ~u : (u | 0x80000000u);
}
__device__ __forceinline__ unsigned short f2bf(float f) {
  unsigned int u = __float_as_uint(f);
  u += 0x7FFFu + ((u >> 16) & 1u);  // rne
  return (unsigned short)(u >> 16);
}
__device__ __forceinline__ float bf_lo(unsigned int u) {
  return __uint_as_float(u << 16);
}
__device__ __forceinline__ float bf_hi(unsigned int u) {
  return __uint_as_float(u & 0xFFFF0000u);
}

// JAX threefry2x32 (20 rounds), exact.
__device__ __forceinline__ void tf2x32(unsigned int k0, unsigned int k1,
                                       unsigned int& x0, unsigned int& x1) {
  unsigned int ks[3] = {k0, k1, k0 ^ k1 ^ 0x1BD11BDAu};
  x0 += ks[0]; x1 += ks[1];
  const unsigned int rotA[4] = {13u, 15u, 26u, 6u};
  const unsigned int rotB[4] = {17u, 29u, 16u, 24u};
#pragma unroll
  for (int g = 0; g < 5; ++g) {
    const unsigned int* rot = (g & 1) ? rotB : rotA;
#pragma unroll
    for (int i = 0; i < 4; ++i) {
      x0 += x1;
      x1 = (x1 << rot[i]) | (x1 >> (32u - rot[i]));
      x1 ^= x0;
    }
    x0 += ks[(g + 1) % 3];
    x1 += ks[(g + 2) % 3] + (unsigned int)(g + 1);
  }
}

// per-block int64-vs-int32 edge layout detect (ballot over odd words)
__device__ __forceinline__ int detect64(const int* ei) {
  int v = 0;
  int tid = threadIdx.x;
  if (tid < 64) v = ei[2 * tid + 1];
  unsigned long long b = __ballot(v != 0);
  return b == 0ull;  // all-high-words-zero -> int64
}

// ---------- MFMA bf16 GEMM (both matmuls in one dispatch, grid-stride) ----

__device__ __forceinline__ int swz(int row, int kb) {
  return row * 256 + (kb ^ ((row & 7) << 4));
}

__global__ __launch_bounds__(256) void gemm_bf16_all(
    const float* __restrict__ Xs, const float* __restrict__ Wl,
    unsigned short* __restrict__ Ys, int NSn, const float* __restrict__ Xm,
    const float* __restrict__ Wr, unsigned short* __restrict__ Ym, int NMn) {
  __shared__ __align__(16) unsigned short As[128 * 128];
  __shared__ __align__(16) unsigned short Bs[128 * 128];
  const int tid = threadIdx.x;
  const int nsb = (NSn + 127) >> 7;
  const int nmb = (NMn + 127) >> 7;

  for (int v = blockIdx.x; v < nsb + nmb; v += gridDim.x) {
    const float* X;
    const float* W;
    unsigned short* Y;
    int N;
    long long r0;
    if (v < nsb) {
      X = Xs; W = Wl; Y = Ys; N = NSn; r0 = (long long)v * 128;
    } else {
      X = Xm; W = Wr; Y = Ym; N = NMn; r0 = (long long)(v - nsb) * 128;
    }
    __syncthreads();  // LDS reuse guard across grid-stride iterations

#pragma unroll 4
    for (int i = 0; i < 16; ++i) {
      int f = i * 256 + tid;
      int row = f >> 5;
      int j = f & 31;
      float4 wv = *(const float4*)(W + row * D + j * 4);
      uint2 wp;
      wp.x = (unsigned int)f2bf(wv.x) | ((unsigned int)f2bf(wv.y) << 16);
      wp.y = (unsigned int)f2bf(wv.z) | ((unsigned int)f2bf(wv.w) << 16);
      *(uint2*)((char*)Bs + swz(row, j * 8)) = wp;
      long long rr = r0 + row;
      if (rr >= N) rr = N - 1;
      float4 xv = *(const float4*)(X + rr * D + j * 4);
      uint2 xp;
      xp.x = (unsigned int)f2bf(xv.x) | ((unsigned int)f2bf(xv.y) << 16);
      xp.y = (unsigned int)f2bf(xv.z) | ((unsigned int)f2bf(xv.w) << 16);
      *(uint2*)((char*)As + swz(row, j * 8)) = xp;
    }
    __syncthreads();

    const int lane = tid & 63;
    const int wid = tid >> 6;
    const int wr = wid >> 1;
    const int wc = wid & 1;
    const int cl = lane & 15;
    const int sub = lane >> 4;

    f32x4 acc[4][4] = {};

#pragma unroll
    for (int ks = 0; ks < 4; ++ks) {
      s16x8 av[4], bv[4];
#pragma unroll
      for (int m = 0; m < 4; ++m)
        av[m] = *(const s16x8*)((const char*)As +
                                swz(wr * 64 + m * 16 + cl, ks * 64 + sub * 16));
#pragma unroll
      for (int n = 0; n < 4; ++n)
        bv[n] = *(const s16x8*)((const char*)Bs +
                                swz(wc * 64 + n * 16 + cl, ks * 64 + sub * 16));
#pragma unroll
      for (int m = 0; m < 4; ++m)
#pragma unroll
        for (int n = 0; n < 4; ++n)
          acc[m][n] = __builtin_amdgcn_mfma_f32_16x16x32_bf16(av[m], bv[n],
                                                              acc[m][n], 0, 0, 0);
    }

#pragma unroll
    for (int m = 0; m < 4; ++m) {
#pragma unroll
      for (int j = 0; j < 4; ++j) {
        long long row = r0 + wr * 64 + m * 16 + sub * 4 + j;
        if (row < N) {
          unsigned short* yp = Y + row * D + wc * 64 + cl;
#pragma unroll
          for (int n = 0; n < 4; ++n) yp[n * 16] = f2bf(acc[m][n][j]);
        }
      }
    }
  }
}

// ---------- edge pass 1: score -> store exp(e), atomicAdd denom ----------
// Inline edge decode; 2048 wg (TLP-bound gather: 72% occ = 50us, 37% = 55us).

__global__ __launch_bounds__(256) void edge_scores(
    const unsigned short* __restrict__ xlh, const unsigned short* __restrict__ xrh,
    const int* __restrict__ ei, const float* __restrict__ att,
    float* __restrict__ e_ex, float* __restrict__ s_sum, int ne, int ns,
    int nm) {
  __shared__ int f64s;
  int tid = threadIdx.x;
  int d64 = detect64(ei);
  if (tid == 0) f64s = d64;
  __syncthreads();
  const int f64 = f64s;

  int lane = tid & 63;
  int q = lane & 15;
  int sub = lane >> 4;
  int wid = (blockIdx.x * 256 + tid) >> 6;
  int nw = (gridDim.x * 256) >> 6;
  float4 a0 = ((const float4*)att)[2 * q];
  float4 a1 = ((const float4*)att)[2 * q + 1];
  for (int e0 = wid * 8; e0 < ne; e0 += nw * 8) {
    int eA = e0 + sub, eB = e0 + 4 + sub;
    int okA = eA < ne, okB = eB < ne;
    int sA = 0, dA = 0, sB = 0, dB = 0;
    if (okA) {
      sA = f64 ? ei[2 * eA] : ei[eA];
      dA = f64 ? ei[2 * ne + 2 * eA] : ei[ne + eA];
      sA = sA < 0 ? 0 : (sA >= ns ? ns - 1 : sA);
      dA = dA < 0 ? 0 : (dA >= nm ? nm - 1 : dA);
    }
    if (okB) {
      sB = f64 ? ei[2 * eB] : ei[eB];
      dB = f64 ? ei[2 * ne + 2 * eB] : ei[ne + eB];
      sB = sB < 0 ? 0 : (sB >= ns ? ns - 1 : sB);
      dB = dB < 0 ? 0 : (dB >= nm ? nm - 1 : dB);
    }
    uint4 lA = *(const uint4*)(xlh + (long long)sA * D + q * 8);
    uint4 rA = *(const uint4*)(xrh + (long long)dA * D + q * 8);
    uint4 lB = *(const uint4*)(xlh + (long long)sB * D + q * 8);
    uint4 rB = *(const uint4*)(xrh + (long long)dB * D + q * 8);
    float z, vA = 0.f, vB = 0.f;
    z = bf_lo(lA.x) + bf_lo(rA.x); vA += (z > 0.f ? z : 0.2f * z) * a0.x;
    z = bf_hi(lA.x) + bf_hi(rA.x); vA += (z > 0.f ? z : 0.2f * z) * a0.y;
    z = bf_lo(lA.y) + bf_lo(rA.y); vA += (z > 0.f ? z : 0.2f * z) * a0.z;
    z = bf_hi(lA.y) + bf_hi(rA.y); vA += (z > 0.f ? z : 0.2f * z) * a0.w;
    z = bf_lo(lA.z) + bf_lo(rA.z); vA += (z > 0.f ? z : 0.2f * z) * a1.x;
    z = bf_hi(lA.z) + bf_hi(rA.z); vA += (z > 0.f ? z : 0.2f * z) * a1.y;
    z = bf_lo(lA.w) + bf_lo(rA.w); vA += (z > 0.f ? z : 0.2f * z) * a1.z;
    z = bf_hi(lA.w) + bf_hi(rA.w); vA += (z > 0.f ? z : 0.2f * z) * a1.w;
    z = bf_lo(lB.x) + bf_lo(rB.x); vB += (z > 0.f ? z : 0.2f * z) * a0.x;
    z = bf_hi(lB.x) + bf_hi(rB.x); vB += (z > 0.f ? z : 0.2f * z) * a0.y;
    z = bf_lo(lB.y) + bf_lo(rB.y); vB += (z > 0.f ? z : 0.2f * z) * a0.z;
    z = bf_hi(lB.y) + bf_hi(rB.y); vB += (z > 0.f ? z : 0.2f * z) * a0.w;
    z = bf_lo(lB.z) + bf_lo(rB.z); vB += (z > 0.f ? z : 0.2f * z) * a1.x;
    z = bf_hi(lB.z) + bf_hi(rB.z); vB += (z > 0.f ? z : 0.2f * z) * a1.y;
    z = bf_lo(lB.w) + bf_lo(rB.w); vB += (z > 0.f ? z : 0.2f * z) * a1.z;
    z = bf_hi(lB.w) + bf_hi(rB.w); vB += (z > 0.f ? z : 0.2f * z) * a1.w;
#pragma unroll
    for (int o = 8; o > 0; o >>= 1) vA += __shfl_xor(vA, o, 64);
#pragma unroll
    for (int o = 8; o > 0; o >>= 1) vB += __shfl_xor(vB, o, 64);
    if (q == 0) {
      if (okA) { float ex = expf(vA); e_ex[eA] = ex; atomicAdd(&s_sum[dA], ex); }
      if (okB) { float ex = expf(vB); e_ex[eB] = ex; atomicAdd(&s_sum[dB], ex); }
    }
  }
}

// ---------- edge pass 2: per-source scalar coefficients (grid-stride) ------

__global__ __launch_bounds__(256) void edge_coef(
    const float* __restrict__ e_ex, const int* __restrict__ ei,
    const float* __restrict__ s_sum, float* __restrict__ coef, int ne, int ns,
    int nm) {
  __shared__ int f64s;
  int tid = threadIdx.x;
  int d64 = detect64(ei);
  if (tid == 0) f64s = d64;
  __syncthreads();
  const int f64 = f64s;
  for (int i = blockIdx.x * 256 + tid; i < ne; i += gridDim.x * 256) {
    int s_ = f64 ? ei[2 * i] : ei[i];
    int d_ = f64 ? ei[2 * ne + 2 * i] : ei[ne + i];
    s_ = s_ < 0 ? 0 : (s_ >= ns ? ns - 1 : s_);
    d_ = d_ < 0 ? 0 : (d_ >= nm ? nm - 1 : d_);
    float w = e_ex[i] / s_sum[d_];
    atomicAdd(&coef[s_], w);
  }
}

// ---------- edge pass 3: g_vec[d] = sum_s coef[s] * xlh[s][d]  (bf16 rows) ----

__global__ __launch_bounds__(256) void weighted_sum(
    const unsigned short* __restrict__ xlh, const float* __restrict__ coef,
    float* __restrict__ g_vec, int ns) {
  __shared__ float red[4][D];
  int lane = threadIdx.x & 63;
  int wv = threadIdx.x >> 6;
  int wid = blockIdx.x * 4 + wv;
  int nw = gridDim.x * 4;
  float ax = 0.f, ay = 0.f;
  for (int s = wid; s < ns; s += nw) {
    float w = coef[s];
    unsigned int x2 = ((const unsigned int*)(xlh + (long long)s * D))[lane];
    ax += w * bf_lo(x2);
    ay += w * bf_hi(x2);
  }
  red[wv][2 * lane] = ax;
  red[wv][2 * lane + 1] = ay;
  __syncthreads();
  if (threadIdx.x < D) {
    float t = red[0][threadIdx.x] + red[1][threadIdx.x] + red[2][threadIdx.x] +
              red[3][threadIdx.x];
    atomicAdd(&g_vec[threadIdx.x], t);
  }
}

// ---------- per step, part 1: gates, 32 blocks, coalesced ----------

__global__ __launch_bounds__(256) void lstm_gates(
    const float* __restrict__ g_vec, const float* __restrict__ conv_bias,
    const float* __restrict__ Wih, const float* __restrict__ Whh,
    const float* __restrict__ bih, const float* __restrict__ bhh,
    const float* __restrict__ emb, const float* __restrict__ logits,
    const unsigned long long* __restrict__ amax,
    const float* __restrict__ sumexp, const float* __restrict__ st_h,
    float* __restrict__ st_gates, float* __restrict__ out, int nm, float nmf,
    int t) {
  __shared__ float vin[D], hprev[D];
  const int tid = threadIdx.x;

  int a = 0;
  if (t > 0) {
    unsigned long long p = amax[t - 1];
    a = (int)(0xFFFFFFFFu - (unsigned int)(p & 0xFFFFFFFFull));
    a = a < 0 ? 0 : (a >= nm ? nm - 1 : a);
  }
  if (t > 0 && blockIdx.x == 0 && tid == 0) {
    out[t - 1] = (float)a;
    out[8 + t - 1] = logits[a] - logf(sumexp[t - 1]);
  }
  if (tid < D) {
    vin[tid] = (t == 0) ? (g_vec[tid] / nmf + conv_bias[tid])
                        : emb[(long long)a * D + tid];
    hprev[tid] = (t == 0) ? 0.f : st_h[tid];
  }
  __syncthreads();

  int r = blockIdx.x * 16 + (tid >> 4);
  int q = tid & 15;
  const float4* wi = (const float4*)(Wih + (long long)r * D + q * 8);
  const float4* wh = (const float4*)(Whh + (long long)r * D + q * 8);
  float4 a0 = wi[0], a1 = wi[1];
  float4 b0 = wh[0], b1 = wh[1];
  int kb = q * 8;
  float s = a0.x * vin[kb] + a0.y * vin[kb + 1] + a0.z * vin[kb + 2] +
            a0.w * vin[kb + 3] + a1.x * vin[kb + 4] + a1.y * vin[kb + 5] +
            a1.z * vin[kb + 6] + a1.w * vin[kb + 7] + b0.x * hprev[kb] +
            b0.y * hprev[kb + 1] + b0.z * hprev[kb + 2] + b0.w * hprev[kb + 3] +
            b1.x * hprev[kb + 4] + b1.y * hprev[kb + 5] + b1.z * hprev[kb + 6] +
            b1.w * hprev[kb + 7];
  s += __shfl_xor(s, 1, 64);
  s += __shfl_xor(s, 2, 64);
  s += __shfl_xor(s, 4, 64);
  s += __shfl_xor(s, 8, 64);
  if (q == 0) st_gates[r] = s + bih[r] + bhh[r];
}

// ---------- per step, part 2: 256 wg grid-stride over W2 rows ----------
// Per block: cell+W1 prologue (redundant), then ~4 chunks of 64 rows;
// (pk,ex) accumulated in registers; ONE atomicMax+atomicAdd per block.

__global__ __launch_bounds__(256) void logits_fused3(
    const float* __restrict__ st_gates, const float* __restrict__ W1,
    const float* __restrict__ b1, const float* __restrict__ W2,
    const float* __restrict__ b2, float* __restrict__ st_c,
    float* __restrict__ st_h, float* __restrict__ logits,
    unsigned long long* __restrict__ amax, float* __restrict__ sumexp,
    int nm, int t) {
  __shared__ float hn_s[D];
  __shared__ float hid_s[D];
  __shared__ unsigned long long pkw[4];
  __shared__ float exw[4];
  const int tid = threadIdx.x;
  const int bid = blockIdx.x;

  if (tid < D) {
    float gi = st_gates[tid], gf = st_gates[D + tid],
          gg = st_gates[2 * D + tid], go = st_gates[3 * D + tid];
    float i_ = 1.f / (1.f + expf(-gi));
    float f_ = 1.f / (1.f + expf(-gf));
    float g_ = tanhf(gg);
    float o_ = 1.f / (1.f + expf(-go));
    float cprev = (t == 0) ? 0.f : st_c[((t & 1) ^ 1) * D + tid];
    float cn = f_ * cprev + i_ * g_;
    float hn = o_ * tanhf(cn);
    hn_s[tid] = hn;
    if (bid == 0) {
      st_c[(t & 1) * D + tid] = cn;
      st_h[tid] = hn;
    }
  }
  __syncthreads();

  if (tid < D) {
    const float4* w = (const float4*)(W1 + tid * D);
    float s0 = 0.f, s1 = 0.f, s2 = 0.f, s3 = 0.f;
#pragma unroll 8
    for (int k = 0; k < 32; ++k) {
      float4 ww = w[k];
      s0 += ww.x * hn_s[4 * k];
      s1 += ww.y * hn_s[4 * k + 1];
      s2 += ww.z * hn_s[4 * k + 2];
      s3 += ww.w * hn_s[4 * k + 3];
    }
    hid_s[tid] = fmaxf(((s0 + s1) + (s2 + s3)) + b1[tid], 0.f);
  }
  __syncthreads();

  // gumbel key for this step
  unsigned int k0 = 0u, k1 = (unsigned int)t;
  tf2x32(0u, 42u, k0, k1);

  const int q = tid & 3;
  float exacc = 0.f;
  unsigned long long pkacc = 0ull;
  for (int r0 = bid * 64; r0 < nm; r0 += gridDim.x * 64) {
    int row = r0 + (tid >> 2);
    if (row < nm) {
      const float4* w = (const float4*)(W2 + (long long)row * D + q * 32);
      float s0 = 0.f, s1 = 0.f, s2 = 0.f, s3 = 0.f;
#pragma unroll
      for (int k = 0; k < 8; ++k) {
        float4 ww = w[k];
        int kb = q * 32 + 4 * k;
        s0 += ww.x * hid_s[kb];
        s1 += ww.y * hid_s[kb + 1];
        s2 += ww.z * hid_s[kb + 2];
        s3 += ww.w * hid_s[kb + 3];
      }
      float s = (s0 + s1) + (s2 + s3);
      s += __shfl_xor(s, 1, 64);
      s += __shfl_xor(s, 2, 64);
      if (q == 0) {
        float lv = s + b2[row];
        logits[row] = lv;
        exacc += expf(lv);
        unsigned int x0 = 0u, x1 = (unsigned int)row;
        tf2x32(k0, k1, x0, x1);
        unsigned int bits = x0 ^ x1;
        float f = __uint_as_float((bits >> 9) | 0x3f800000u) - 1.0f;
        const float tiny = 1.1754943508222875e-38f;
        float u = fmaxf(tiny, f * (1.0f - tiny) + tiny);
        float gmb = -logf(-logf(u));
        float pert = lv + gmb;
        unsigned long long pk = ((unsigned long long)encf(pert) << 32) |
                                (unsigned long long)(0xFFFFFFFFu - (unsigned int)row);
        pkacc = pk > pkacc ? pk : pkacc;
      }
    }
  }
  // wave-level reduce (max pk, sum ex)
#pragma unroll
  for (int o = 32; o > 0; o >>= 1) {
    unsigned long long pko = __shfl_xor(pkacc, o, 64);
    pkacc = pko > pkacc ? pko : pkacc;
    exacc += __shfl_xor(exacc, o, 64);
  }
  int wv = tid >> 6;
  if ((tid & 63) == 0) {
    pkw[wv] = pkacc;
    exw[wv] = exacc;
  }
  __syncthreads();
  if (tid == 0) {
    unsigned long long pm = pkw[0];
    pm = pkw[1] > pm ? pkw[1] : pm;
    pm = pkw[2] > pm ? pkw[2] : pm;
    pm = pkw[3] > pm ? pkw[3] : pm;
    atomicMax(&amax[t], pm);
    atomicAdd(&sumexp[t], ((exw[0] + exw[1]) + (exw[2] + exw[3])));
  }
}

// ---------- final outputs ----------

__global__ __launch_bounds__(128) void final_out(
    const float* __restrict__ h, const float* __restrict__ c,
    const float* __restrict__ logits, const unsigned long long* __restrict__ amax,
    const float* __restrict__ sumexp, float* __restrict__ out, int nm) {
  int tid = threadIdx.x;
  if (tid == 0) {
    unsigned long long p = amax[7];
    int a = (int)(0xFFFFFFFFu - (unsigned int)(p & 0xFFFFFFFFull));
    a = a < 0 ? 0 : (a >= nm ? nm - 1 : a);
    out[7] = (float)a;
    out[15] = logits[a] - logf(sumexp[7]);
  }
  out[16 + tid] = h[tid];
  out[144 + tid] = c[tid];
}

// ---------- launch ----------

extern "C" void kernel_launch(void* const* d_in, const int* in_sizes, int n_in,
                              void* d_out, int out_size, void* d_ws, size_t ws_size,
                              hipStream_t stream) {
  const float* state_features = (const float*)d_in[0];
  const float* model_features = (const float*)d_in[1];
  const int* edge_index = (const int*)d_in[2];
  const float* W_l = (const float*)d_in[3];
  const float* W_r = (const float*)d_in[4];
  const float* att = (const float*)d_in[5];
  const float* conv_bias = (const float*)d_in[6];
  const float* Wih = (const float*)d_in[7];
  const float* Whh = (const float*)d_in[8];
  const float* bih = (const float*)d_in[9];
  const float* bhh = (const float*)d_in[10];
  const float* W1 = (const float*)d_in[11];
  const float* b1 = (const float*)d_in[12];
  const float* W2 = (const float*)d_in[13];
  const float* b2 = (const float*)d_in[14];
  const float* emb = (const float*)d_in[15];
  float* out = (float*)d_out;

  const int NS = in_sizes[0] / D;
  const int NM = in_sizes[1] / D;
  const int E = in_sizes[2] / 2;

  char* ws = (char*)d_ws;
  size_t off = 0;
  auto alloc = [&](size_t bytes) -> void* {
    void* p = ws + off;
    off = (off + bytes + 255) & ~(size_t)255;
    return p;
  };
  unsigned short* xlh = (unsigned short*)alloc((size_t)NS * D * 2);
  unsigned short* xrh = (unsigned short*)alloc((size_t)NM * D * 2);
  float* e_ex = (float*)alloc((size_t)E * 4);
  float* logits = (float*)alloc((size_t)NM * 4);
  float* st_h = (float*)alloc(D * 4);
  float* st_c = (float*)alloc(2 * D * 4);
  float* st_gates = (float*)alloc(4 * D * 4);
  size_t zstart = off;
  float* s_sum = (float*)alloc((size_t)NM * 4);
  float* coef = (float*)alloc((size_t)NS * 4);
  float* g_vec = (float*)alloc(D * 4);
  float* st_sumexp = (float*)alloc(8 * 4);
  unsigned long long* st_amax = (unsigned long long*)alloc(8 * 8);
  size_t zend = off;

  hipMemsetAsync(ws + zstart, 0, zend - zstart, stream);

  gemm_bf16_all<<<256, 256, 0, stream>>>(state_features, W_l, xlh, NS,
                                         model_features, W_r, xrh, NM);

  edge_scores<<<2048, 256, 0, stream>>>(xlh, xrh, edge_index, att, e_ex,
                                        s_sum, E, NS, NM);
  edge_coef<<<1024, 256, 0, stream>>>(e_ex, edge_index, s_sum, coef, E, NS,
                                      NM);
  weighted_sum<<<512, 256, 0, stream>>>(xlh, coef, g_vec, NS);

  for (int t = 0; t < 8; ++t) {
    lstm_gates<<<32, 256, 0, stream>>>(g_vec, conv_bias, Wih, Whh, bih, bhh,
                                       emb, logits, st_amax, st_sumexp, st_h,
                                       st_gates, out, NM, (float)NM, t);
    logits_fused3<<<256, 256, 0, stream>>>(st_gates, W1, b1, W2, b2, st_c,
                                           st_h, logits, st_amax, st_sumexp,
                                           NM, t);
  }

  final_out<<<1, 128, 0, stream>>>(st_h, st_c + D, logits, st_amax, st_sumexp,
                                   out, NM);
}